// Round 5
// baseline (310.616 us; speedup 1.0000x reference)
//
#include <hip/hip_runtime.h>
#include <math.h>

// LipsNet R5. B=8192, D_IN=256, H=256, D_OUT=64.
// k0: swizzle W2^T, W1^T (Jacobian A-frags) + W3 (A-frag) to bf16 in ws. [R4-validated]
// k1: fp32 forward, 16 samples/block, 128 thr, G=8 register tile (bit-identical FMA order
//     to R4's validated k1). Writes r1,r2 masks (u8) + f (fp32) to ws.
// k2: per 2-sample block (512 thr): A1^T = W2T @ (W3 .* r2)^T ; M^T = W1T @ (A1^T .* r1);
//     W3 B-frags built in registers (lane-local passthrough, no LDS round-trip);
//     Vh uses +16B row padding (stride 264 halfwords) instead of XOR swizzle.
//
// MFMA 16x16x32 layouts (validated R2/R4):
//   A[m][k]: m = lane&15, k = (lane>>4)*8 + i
//   B[k][n]: n = lane&15, k = (lane>>4)*8 + i
//   C/D:     col = lane&15, row = (lane>>4)*4 + reg

typedef float  f32x4  __attribute__((ext_vector_type(4)));
typedef short  bf16x8 __attribute__((ext_vector_type(8)));
typedef unsigned int   uint;
typedef unsigned short ushort;
typedef unsigned char  uchar;
typedef uint   u32x4  __attribute__((ext_vector_type(4)));
typedef uint   u32x2  __attribute__((ext_vector_type(2)));

// ws byte offsets
#define W2TA_OFF 0u        // 16rb x 8ks x 64l x 16B = 131072
#define W1TA_OFF 131072u   // 131072
#define W3A_OFF  262144u   // 4rb x 8ks x 64l x 16B = 32768
#define F_OFF    294912u   // 8192x64 fp32 = 2097152
#define R1_OFF   2392064u  // 8192x256 u8 = 2097152
#define R2_OFF   4489216u  // 2097152
// total 6586368 B

#define VROW 264           // Vh row stride in halfwords (256 + 8 pad = 16B pad)
#define VS   16896         // per-sample Vh halfwords (64 * 264)

__device__ __forceinline__ ushort f2bf(float f) {
    uint u = __builtin_bit_cast(uint, f);
    u += 0x7FFFu + ((u >> 16) & 1u);          // RNE
    return (ushort)(u >> 16);
}
// halfword and-mask from two mask bytes of u at bit positions sh, sh+8
__device__ __forceinline__ uint hm2(uint u, int sh) {
    return (((u >> sh) & 0xFFu)   ? 0xFFFFu     : 0u) |
           (((u >> sh) & 0xFF00u) ? 0xFFFF0000u : 0u);
}

// ---------------- k0: weight prep (R4-validated) ----------------
__global__ __launch_bounds__(256) void k0_prep(
    const float* __restrict__ W1, const float* __restrict__ W2,
    const float* __restrict__ W3, char* __restrict__ ws)
{
    const int id = blockIdx.x * 256 + threadIdx.x;
    if (id >= 18432) return;
    const int grp = id >> 13;          // 0,1, 2(partial: 2048)
    const int fid = id & 8191;
    const int l = fid & 63, ks = (fid >> 6) & 7, rb = fid >> 9;
    const int m = l & 15, q = l >> 4;
    const int k0 = ks * 32 + q * 8;
    ushort h[8];
    uint dstoff;
    if (grp == 0) {          // W2TA: A[m][k] = W2[k][rb*16+m]
        const int e = rb * 16 + m;
        #pragma unroll
        for (int i = 0; i < 8; ++i) h[i] = f2bf(W2[(k0 + i) * 256 + e]);
        dstoff = W2TA_OFF;
    } else if (grp == 1) {   // W1TA: A[m][k] = W1[k][rb*16+m]
        const int n = rb * 16 + m;
        #pragma unroll
        for (int i = 0; i < 8; ++i) h[i] = f2bf(W1[(k0 + i) * 256 + n]);
        dstoff = W1TA_OFF;
    } else {                 // W3A: A[m][k] = W3[rb*16+m][k]  (fid 0..2047, rb 0..3)
        const float* p = W3 + (rb * 16 + m) * 256 + k0;
        #pragma unroll
        for (int i = 0; i < 8; ++i) h[i] = f2bf(p[i]);
        dstoff = W3A_OFF;
    }
    u32x4 v;
    v.x = (uint)h[0] | ((uint)h[1] << 16);
    v.y = (uint)h[2] | ((uint)h[3] << 16);
    v.z = (uint)h[4] | ((uint)h[5] << 16);
    v.w = (uint)h[6] | ((uint)h[7] << 16);
    ((u32x4*)(ws + dstoff))[fid] = v;
}

// ---------------- k1: fp32 forward, 16 samples/block, G=8 tile ----------------
__device__ __forceinline__ void layer256_g8(
    const f32x4* __restrict__ in, const f32x4* __restrict__ Wm,
    const float* __restrict__ bias, int gi, int n0, float acc[8][4])
{
    #pragma unroll
    for (int j = 0; j < 4; ++j) {
        const float bv = bias[n0 + j];
        #pragma unroll
        for (int gg = 0; gg < 8; ++gg) acc[gg][j] = bv;
    }
    #pragma unroll 2
    for (int dq = 0; dq < 64; ++dq) {
        f32x4 a[8], w[4];
        #pragma unroll
        for (int gg = 0; gg < 8; ++gg) a[gg] = in[(gi + gg) * 65 + dq];
        #pragma unroll
        for (int j = 0; j < 4; ++j) w[j] = Wm[(n0 + j) * 64 + dq];
        #pragma unroll
        for (int gg = 0; gg < 8; ++gg)
            #pragma unroll
            for (int j = 0; j < 4; ++j) {
                float s = acc[gg][j];
                s = fmaf(a[gg].x, w[j].x, s);
                s = fmaf(a[gg].y, w[j].y, s);
                s = fmaf(a[gg].z, w[j].z, s);
                s = fmaf(a[gg].w, w[j].w, s);
                acc[gg][j] = s;
            }
    }
}

__global__ __launch_bounds__(128) void k1_forward(
    const float* __restrict__ x,
    const float* __restrict__ W1, const float* __restrict__ b1,
    const float* __restrict__ W2, const float* __restrict__ b2,
    const float* __restrict__ W3, const float* __restrict__ b3,
    char* __restrict__ ws)
{
    __shared__ f32x4 xsv[1040];   // [16][65]
    __shared__ f32x4 h1v[1040];
    __shared__ f32x4 h2v[1040];
    float* h1f = (float*)h1v;
    float* h2f = (float*)h2v;
    float* fws = (float*)(ws + F_OFF);
    uchar* r1g = (uchar*)(ws + R1_OFF);
    uchar* r2g = (uchar*)(ws + R2_OFF);

    const int t = threadIdx.x;       // 0..127
    const int g0 = blockIdx.x * 16;
    const f32x4* X4 = (const f32x4*)x;

    #pragma unroll
    for (int i = 0; i < 8; ++i) {
        const int fid = t + 128 * i;
        const int g = fid >> 6, dq = fid & 63;
        xsv[g * 65 + dq] = X4[(size_t)(g0 + g) * 64 + dq];
    }
    __syncthreads();

    const int gi = (t & 1) * 8;
    const int n0 = (t >> 1) * 4;
    const f32x4* W1_4 = (const f32x4*)W1;
    const f32x4* W2_4 = (const f32x4*)W2;
    const f32x4* W3_4 = (const f32x4*)W3;

    float acc[8][4];
    // layer 1
    layer256_g8(xsv, W1_4, b1, gi, n0, acc);
    #pragma unroll
    for (int gg = 0; gg < 8; ++gg)
        #pragma unroll
        for (int j = 0; j < 4; ++j) {
            const float v = acc[gg][j];
            r1g[(size_t)(g0 + gi + gg) * 256 + (n0 + j)] = (uchar)(v > 0.0f);
            h1f[(gi + gg) * 260 + (n0 + j)] = fmaxf(v, 0.0f);
        }
    __syncthreads();
    // layer 2
    layer256_g8(h1v, W2_4, b2, gi, n0, acc);
    #pragma unroll
    for (int gg = 0; gg < 8; ++gg)
        #pragma unroll
        for (int j = 0; j < 4; ++j) {
            const float v = acc[gg][j];
            r2g[(size_t)(g0 + gi + gg) * 256 + (n0 + j)] = (uchar)(v > 0.0f);
            h2f[(gi + gg) * 260 + (n0 + j)] = fmaxf(v, 0.0f);
        }
    __syncthreads();
    // layer 3: j0 = t>>1 (0..63), 8 samples each
    {
        const int j0 = t >> 1;
        float a3[8];
        #pragma unroll
        for (int gg = 0; gg < 8; ++gg) a3[gg] = b3[j0];
        #pragma unroll 2
        for (int dq = 0; dq < 64; ++dq) {
            const f32x4 wv = W3_4[j0 * 64 + dq];
            #pragma unroll
            for (int gg = 0; gg < 8; ++gg) {
                const f32x4 a = h2v[(gi + gg) * 65 + dq];
                float s = a3[gg];
                s = fmaf(a.x, wv.x, s);
                s = fmaf(a.y, wv.y, s);
                s = fmaf(a.z, wv.z, s);
                s = fmaf(a.w, wv.w, s);
                a3[gg] = s;
            }
        }
        #pragma unroll
        for (int gg = 0; gg < 8; ++gg)
            fws[(size_t)(g0 + gi + gg) * 64 + j0] = a3[gg];
    }
}

// ---------------- k2: Jacobian norm + output, 2 samples/block, 512 thr ----------------
__global__ __launch_bounds__(512, 4) void k2_jac(
    const char* __restrict__ ws, const float* __restrict__ kp,
    float* __restrict__ out)
{
    __shared__ ushort Vh[2 * VS];          // 67584 B, +16B row pad (conflict-free)
    __shared__ uint r1u[2][64], r2u[2][64];
    __shared__ float red[2][8];

    const int t = threadIdx.x, w = t >> 6, l = t & 63;
    const int m = l & 15, q = l >> 4;
    const int b = blockIdx.x;

    if (t < 128) {
        const int s = t >> 6, i = t & 63;
        r1u[s][i] = ((const uint*)(ws + R1_OFF))[(size_t)(b * 2 + s) * 64 + i];
        r2u[s][i] = ((const uint*)(ws + R2_OFF))[(size_t)(b * 2 + s) * 64 + i];
    }
    __syncthreads();

    // ---- GEMM1: A1^T = W2T @ (W3 .* r2)^T ; W3 B-frags built in registers.
    //      (lane-local: the masked W3 A-frag slot a lane holds IS its B-frag slot)
    f32x4 acc[2][2][4];                    // [s][rp][cb]
    #pragma unroll
    for (int s = 0; s < 2; ++s)
        #pragma unroll
        for (int rp = 0; rp < 2; ++rp)
            #pragma unroll
            for (int cb = 0; cb < 4; ++cb) acc[s][rp][cb] = (f32x4){0.f, 0.f, 0.f, 0.f};

    {
        const bf16x8* W2Tf = (const bf16x8*)(ws + W2TA_OFF);
        const u32x4*  W3Av = (const u32x4*)(ws + W3A_OFF);
        #pragma unroll
        for (int ks = 0; ks < 8; ++ks) {
            bf16x8 a[2];
            #pragma unroll
            for (int rp = 0; rp < 2; ++rp) a[rp] = W2Tf[((2 * w + rp) * 8 + ks) * 64 + l];
            const int du = ks * 8 + q * 2;         // r2 word idx for d = ks*32+q*8
            uint mw[2][4];
            #pragma unroll
            for (int s = 0; s < 2; ++s) {
                const uint u0 = r2u[s][du], u1 = r2u[s][du + 1];
                mw[s][0] = hm2(u0, 0);  mw[s][1] = hm2(u0, 16);
                mw[s][2] = hm2(u1, 0);  mw[s][3] = hm2(u1, 16);
            }
            #pragma unroll
            for (int cb = 0; cb < 4; ++cb) {
                const u32x4 wv = W3Av[(cb * 8 + ks) * 64 + l];
                #pragma unroll
                for (int s = 0; s < 2; ++s) {
                    u32x4 vv;
                    vv.x = wv.x & mw[s][0];
                    vv.y = wv.y & mw[s][1];
                    vv.z = wv.z & mw[s][2];
                    vv.w = wv.w & mw[s][3];
                    const bf16x8 bb = __builtin_bit_cast(bf16x8, vv);
                    #pragma unroll
                    for (int rp = 0; rp < 2; ++rp)
                        acc[s][rp][cb] = __builtin_amdgcn_mfma_f32_16x16x32_bf16(a[rp], bb, acc[s][rp][cb], 0, 0, 0);
                }
            }
        }
    }

    // ---- Phase C: Vh[s][j][e] = A1^T[e][j] * r1[e] (bf16, padded rows, b64 writes)
    {
        #pragma unroll
        for (int s = 0; s < 2; ++s)
            #pragma unroll
            for (int rp = 0; rp < 2; ++rp) {
                const int rb = 2 * w + rp;
                const int e0 = rb * 16 + q * 4;
                const uint mu = r1u[s][rb * 4 + q];
                #pragma unroll
                for (int cb = 0; cb < 4; ++cb) {
                    const f32x4 av = acc[s][rp][cb];
                    const float v0 = (mu & 0xFFu)       ? av.x : 0.f;
                    const float v1 = (mu & 0xFF00u)     ? av.y : 0.f;
                    const float v2 = (mu & 0xFF0000u)   ? av.z : 0.f;
                    const float v3 = (mu & 0xFF000000u) ? av.w : 0.f;
                    u32x2 p;
                    p.x = (uint)f2bf(v0) | ((uint)f2bf(v1) << 16);
                    p.y = (uint)f2bf(v2) | ((uint)f2bf(v3) << 16);
                    const int j = cb * 16 + m;
                    *(u32x2*)&Vh[s * VS + j * VROW + e0] = p;
                }
            }
    }
    __syncthreads();

    // ---- GEMM2: M^T = W1T @ (Vh as B) ; wave w owns rb_n in {2w, 2w+1}
    f32x4 acc2[2][2][4];
    #pragma unroll
    for (int s = 0; s < 2; ++s)
        #pragma unroll
        for (int rp = 0; rp < 2; ++rp)
            #pragma unroll
            for (int cb = 0; cb < 4; ++cb) acc2[s][rp][cb] = (f32x4){0.f, 0.f, 0.f, 0.f};

    {
        const bf16x8* W1Tf = (const bf16x8*)(ws + W1TA_OFF);
        #pragma unroll
        for (int ks = 0; ks < 8; ++ks) {
            bf16x8 a[2];
            #pragma unroll
            for (int rp = 0; rp < 2; ++rp) a[rp] = W1Tf[((2 * w + rp) * 8 + ks) * 64 + l];
            const int c0 = ks * 32 + q * 8;
            #pragma unroll
            for (int s = 0; s < 2; ++s)
                #pragma unroll
                for (int cb = 0; cb < 4; ++cb) {
                    const int j = cb * 16 + m;
                    const bf16x8 bb = *(const bf16x8*)&Vh[s * VS + j * VROW + c0];
                    #pragma unroll
                    for (int rp = 0; rp < 2; ++rp)
                        acc2[s][rp][cb] = __builtin_amdgcn_mfma_f32_16x16x32_bf16(a[rp], bb, acc2[s][rp][cb], 0, 0, 0);
                }
        }
    }

    // ---- reduce ||M_s||_F^2
    {
        float ps0 = 0.f, ps1 = 0.f;
        #pragma unroll
        for (int rp = 0; rp < 2; ++rp)
            #pragma unroll
            for (int cb = 0; cb < 4; ++cb) {
                const f32x4 a0 = acc2[0][rp][cb], a1 = acc2[1][rp][cb];
                ps0 = fmaf(a0.x, a0.x, ps0); ps0 = fmaf(a0.y, a0.y, ps0);
                ps0 = fmaf(a0.z, a0.z, ps0); ps0 = fmaf(a0.w, a0.w, ps0);
                ps1 = fmaf(a1.x, a1.x, ps1); ps1 = fmaf(a1.y, a1.y, ps1);
                ps1 = fmaf(a1.z, a1.z, ps1); ps1 = fmaf(a1.w, a1.w, ps1);
            }
        #pragma unroll
        for (int off = 32; off > 0; off >>= 1) {
            ps0 += __shfl_down(ps0, off, 64);
            ps1 += __shfl_down(ps1, off, 64);
        }
        if (l == 0) { red[0][w] = ps0; red[1][w] = ps1; }
    }
    __syncthreads();

    if (t < 128) {
        const int s = t >> 6, j = t & 63;
        float S = 0.f;
        #pragma unroll
        for (int i = 0; i < 8; ++i) S += red[s][i];
        const float* fws = (const float*)(ws + F_OFF);
        const float f = fws[(size_t)(b * 2 + s) * 64 + j];
        const float kv = kp[0];
        const float ksp = fmaxf(kv, 0.0f) + log1pf(expf(-fabsf(kv)));
        out[(size_t)(b * 2 + s) * 64 + j] = tanhf(ksp * f / (sqrtf(S) + 1e-4f));
    }
}

extern "C" void kernel_launch(void* const* d_in, const int* in_sizes, int n_in,
                              void* d_out, int out_size, void* d_ws, size_t ws_size,
                              hipStream_t stream) {
    const float* x  = (const float*)d_in[0];
    const float* W1 = (const float*)d_in[1];
    const float* b1 = (const float*)d_in[2];
    const float* W2 = (const float*)d_in[3];
    const float* b2 = (const float*)d_in[4];
    const float* W3 = (const float*)d_in[5];
    const float* b3 = (const float*)d_in[6];
    const float* kp = (const float*)d_in[7];
    char* ws = (char*)d_ws;

    k0_prep<<<72, 256, 0, stream>>>(W1, W2, W3, ws);
    k1_forward<<<512, 128, 0, stream>>>(x, W1, b1, W2, b2, W3, b3, ws);
    k2_jac<<<4096, 512, 0, stream>>>(ws, kp, (float*)d_out);
}

// Round 6
// 265.710 us; speedup vs baseline: 1.1690x; 1.1690x over previous
//
#include <hip/hip_runtime.h>
#include <math.h>

// LipsNet R6. B=8192, D_IN=256, H=256, D_OUT=64.
// k0: swizzle W2^T, W1^T (Jacobian A-frags) + W3 (A-frag) to bf16 in ws. [R4-validated]
// k1: fp32 forward, 8 samples/block, 256 thr, G=2 tile, 1024 blocks (occupancy fix:
//     25 KB LDS -> 4+ blocks/CU, 16 waves/CU vs R4's 8).
// k2: R4-validated verbatim: per 2-sample block (512 thr):
//     A1^T = W2T @ (W3 .* r2)^T ; M^T = W1T @ (A1^T .* r1);
//     out = tanh(softplus(k) * f / (||M||_F + eps)).
//
// MFMA 16x16x32 layouts (validated R2/R4):
//   A[m][k]: m = lane&15, k = (lane>>4)*8 + i
//   B[k][n]: n = lane&15, k = (lane>>4)*8 + i
//   C/D:     col = lane&15, row = (lane>>4)*4 + reg

typedef float  f32x4  __attribute__((ext_vector_type(4)));
typedef short  bf16x8 __attribute__((ext_vector_type(8)));
typedef unsigned int   uint;
typedef unsigned short ushort;
typedef unsigned char  uchar;
typedef uint   u32x4  __attribute__((ext_vector_type(4)));
typedef uint   u32x2  __attribute__((ext_vector_type(2)));

// ws byte offsets
#define W2TA_OFF 0u        // 16rb x 8ks x 64l x 16B = 131072
#define W1TA_OFF 131072u   // 131072
#define W3A_OFF  262144u   // 4rb x 8ks x 64l x 16B = 32768
#define F_OFF    294912u   // 8192x64 fp32 = 2097152
#define R1_OFF   2392064u  // 8192x256 u8 = 2097152
#define R2_OFF   4489216u  // 2097152
// total 6586368 B

__device__ __forceinline__ ushort f2bf(float f) {
    uint u = __builtin_bit_cast(uint, f);
    u += 0x7FFFu + ((u >> 16) & 1u);          // RNE
    return (ushort)(u >> 16);
}
// halfword and-mask from two mask bytes of u at bit positions sh, sh+8
__device__ __forceinline__ uint hm2(uint u, int sh) {
    return (((u >> sh) & 0xFFu)   ? 0xFFFFu     : 0u) |
           (((u >> sh) & 0xFF00u) ? 0xFFFF0000u : 0u);
}

// ---------------- k0: weight prep (R4-validated) ----------------
__global__ __launch_bounds__(256) void k0_prep(
    const float* __restrict__ W1, const float* __restrict__ W2,
    const float* __restrict__ W3, char* __restrict__ ws)
{
    const int id = blockIdx.x * 256 + threadIdx.x;
    if (id >= 18432) return;
    const int grp = id >> 13;          // 0,1, 2(partial: 2048)
    const int fid = id & 8191;
    const int l = fid & 63, ks = (fid >> 6) & 7, rb = fid >> 9;
    const int m = l & 15, q = l >> 4;
    const int k0 = ks * 32 + q * 8;
    ushort h[8];
    uint dstoff;
    if (grp == 0) {          // W2TA: A[m][k] = W2[k][rb*16+m]
        const int e = rb * 16 + m;
        #pragma unroll
        for (int i = 0; i < 8; ++i) h[i] = f2bf(W2[(k0 + i) * 256 + e]);
        dstoff = W2TA_OFF;
    } else if (grp == 1) {   // W1TA: A[m][k] = W1[k][rb*16+m]
        const int n = rb * 16 + m;
        #pragma unroll
        for (int i = 0; i < 8; ++i) h[i] = f2bf(W1[(k0 + i) * 256 + n]);
        dstoff = W1TA_OFF;
    } else {                 // W3A: A[m][k] = W3[rb*16+m][k]  (fid 0..2047, rb 0..3)
        const float* p = W3 + (rb * 16 + m) * 256 + k0;
        #pragma unroll
        for (int i = 0; i < 8; ++i) h[i] = f2bf(p[i]);
        dstoff = W3A_OFF;
    }
    u32x4 v;
    v.x = (uint)h[0] | ((uint)h[1] << 16);
    v.y = (uint)h[2] | ((uint)h[3] << 16);
    v.z = (uint)h[4] | ((uint)h[5] << 16);
    v.w = (uint)h[6] | ((uint)h[7] << 16);
    ((u32x4*)(ws + dstoff))[fid] = v;
}

// ---------------- k1: fp32 forward, 8 samples/block, G=2 tile ----------------
__device__ __forceinline__ void layer256_g2(
    const f32x4* __restrict__ in, const f32x4* __restrict__ Wm,
    const float* __restrict__ bias, int gi, int n0, float acc[2][4])
{
    #pragma unroll
    for (int j = 0; j < 4; ++j) {
        const float bv = bias[n0 + j];
        #pragma unroll
        for (int gg = 0; gg < 2; ++gg) acc[gg][j] = bv;
    }
    #pragma unroll 4
    for (int dq = 0; dq < 64; ++dq) {
        f32x4 a[2], w[4];
        #pragma unroll
        for (int gg = 0; gg < 2; ++gg) a[gg] = in[(gi + gg) * 65 + dq];
        #pragma unroll
        for (int j = 0; j < 4; ++j) w[j] = Wm[(n0 + j) * 64 + dq];
        #pragma unroll
        for (int gg = 0; gg < 2; ++gg)
            #pragma unroll
            for (int j = 0; j < 4; ++j) {
                float s = acc[gg][j];
                s = fmaf(a[gg].x, w[j].x, s);
                s = fmaf(a[gg].y, w[j].y, s);
                s = fmaf(a[gg].z, w[j].z, s);
                s = fmaf(a[gg].w, w[j].w, s);
                acc[gg][j] = s;
            }
    }
}

__global__ __launch_bounds__(256) void k1_forward(
    const float* __restrict__ x,
    const float* __restrict__ W1, const float* __restrict__ b1,
    const float* __restrict__ W2, const float* __restrict__ b2,
    const float* __restrict__ W3, const float* __restrict__ b3,
    char* __restrict__ ws)
{
    __shared__ f32x4 xsv[520];    // [8][65]
    __shared__ f32x4 h1v[520];
    __shared__ f32x4 h2v[520];
    float* h1f = (float*)h1v;
    float* h2f = (float*)h2v;
    float* fws = (float*)(ws + F_OFF);
    uchar* r1g = (uchar*)(ws + R1_OFF);
    uchar* r2g = (uchar*)(ws + R2_OFF);

    const int t = threadIdx.x;       // 0..255
    const int g0 = blockIdx.x * 8;
    const f32x4* X4 = (const f32x4*)x;

    #pragma unroll
    for (int i = 0; i < 2; ++i) {
        const int fid = t + 256 * i;
        const int g = fid >> 6, dq = fid & 63;
        xsv[g * 65 + dq] = X4[(size_t)(g0 + g) * 64 + dq];
    }
    __syncthreads();

    const int gi = (t & 3) * 2;      // 4 groups x 2 samples = 8
    const int n0 = (t >> 2) * 4;     // 64 neuron-quads
    const f32x4* W1_4 = (const f32x4*)W1;
    const f32x4* W2_4 = (const f32x4*)W2;
    const f32x4* W3_4 = (const f32x4*)W3;

    float acc[2][4];
    // layer 1
    layer256_g2(xsv, W1_4, b1, gi, n0, acc);
    #pragma unroll
    for (int gg = 0; gg < 2; ++gg)
        #pragma unroll
        for (int j = 0; j < 4; ++j) {
            const float v = acc[gg][j];
            r1g[(size_t)(g0 + gi + gg) * 256 + (n0 + j)] = (uchar)(v > 0.0f);
            h1f[(gi + gg) * 260 + (n0 + j)] = fmaxf(v, 0.0f);
        }
    __syncthreads();
    // layer 2
    layer256_g2(h1v, W2_4, b2, gi, n0, acc);
    #pragma unroll
    for (int gg = 0; gg < 2; ++gg)
        #pragma unroll
        for (int j = 0; j < 4; ++j) {
            const float v = acc[gg][j];
            r2g[(size_t)(g0 + gi + gg) * 256 + (n0 + j)] = (uchar)(v > 0.0f);
            h2f[(gi + gg) * 260 + (n0 + j)] = fmaxf(v, 0.0f);
        }
    __syncthreads();
    // layer 3: j0 = t>>2 (0..63), 2 samples each (4 thread-groups cover 8 samples)
    {
        const int j0 = t >> 2;
        float a3[2];
        #pragma unroll
        for (int gg = 0; gg < 2; ++gg) a3[gg] = b3[j0];
        #pragma unroll 4
        for (int dq = 0; dq < 64; ++dq) {
            const f32x4 wv = W3_4[j0 * 64 + dq];
            #pragma unroll
            for (int gg = 0; gg < 2; ++gg) {
                const f32x4 a = h2v[(gi + gg) * 65 + dq];
                float s = a3[gg];
                s = fmaf(a.x, wv.x, s);
                s = fmaf(a.y, wv.y, s);
                s = fmaf(a.z, wv.z, s);
                s = fmaf(a.w, wv.w, s);
                a3[gg] = s;
            }
        }
        #pragma unroll
        for (int gg = 0; gg < 2; ++gg)
            fws[(size_t)(g0 + gi + gg) * 64 + j0] = a3[gg];
    }
}

// ---------------- k2: Jacobian norm + output, 2 samples/block, 512 thr (R4-validated) ----------------
__global__ __launch_bounds__(512, 4) void k2_jac(
    const char* __restrict__ ws, const float* __restrict__ kp,
    float* __restrict__ out)
{
    __shared__ char Buf[65536];            // per sample 32 KB: Bfrag1 then Vh (overlaid)
    __shared__ uint r1u[2][64], r2u[2][64];
    __shared__ float red[2][8];

    const int t = threadIdx.x, w = t >> 6, l = t & 63;
    const int m = l & 15, q = l >> 4;
    const int b = blockIdx.x;

    if (t < 128) {
        const int s = t >> 6, i = t & 63;
        r1u[s][i] = ((const uint*)(ws + R1_OFF))[(size_t)(b * 2 + s) * 64 + i];
        r2u[s][i] = ((const uint*)(ws + R2_OFF))[(size_t)(b * 2 + s) * 64 + i];
    }
    __syncthreads();

    // ---- Phase A: build Bf1[s] = (W3 .* r2_s)^T B-frags (8 frags per wave)
    {
        const u32x4* W3Av = (const u32x4*)(ws + W3A_OFF);
        u32x4* BufV = (u32x4*)Buf;
        #pragma unroll
        for (int ii = 0; ii < 8; ++ii) {
            const int id = w * 8 + ii;
            const int s = id >> 5, cb = (id >> 3) & 3, ks = id & 7;
            u32x4 v = W3Av[(cb * 8 + ks) * 64 + l];
            const int du = ks * 8 + q * 2;            // (d0>>2), d0 = ks*32+q*8
            const uint u0 = r2u[s][du], u1 = r2u[s][du + 1];
            v.x &= hm2(u0, 0);  v.y &= hm2(u0, 16);
            v.z &= hm2(u1, 0);  v.w &= hm2(u1, 16);
            BufV[s * 2048 + (cb * 8 + ks) * 64 + l] = v;
        }
    }
    __syncthreads();

    // ---- GEMM1: A1^T = W2T @ Bf1 ; wave w owns rb in {2w, 2w+1}, both samples, all cb
    f32x4 acc[2][2][4];                    // [s][rp][cb]
    #pragma unroll
    for (int s = 0; s < 2; ++s)
        #pragma unroll
        for (int rp = 0; rp < 2; ++rp)
            #pragma unroll
            for (int cb = 0; cb < 4; ++cb) acc[s][rp][cb] = (f32x4){0.f, 0.f, 0.f, 0.f};

    {
        const bf16x8* W2Tf = (const bf16x8*)(ws + W2TA_OFF);
        const bf16x8* BufF = (const bf16x8*)Buf;
        #pragma unroll
        for (int ks = 0; ks < 8; ++ks) {
            bf16x8 a[2];
            #pragma unroll
            for (int rp = 0; rp < 2; ++rp) a[rp] = W2Tf[((2 * w + rp) * 8 + ks) * 64 + l];
            #pragma unroll
            for (int s = 0; s < 2; ++s)
                #pragma unroll
                for (int cb = 0; cb < 4; ++cb) {
                    const bf16x8 bb = BufF[s * 2048 + (cb * 8 + ks) * 64 + l];
                    #pragma unroll
                    for (int rp = 0; rp < 2; ++rp)
                        acc[s][rp][cb] = __builtin_amdgcn_mfma_f32_16x16x32_bf16(a[rp], bb, acc[s][rp][cb], 0, 0, 0);
                }
        }
    }
    __syncthreads();   // all Bf1 reads done before overlay

    // ---- Phase C: Vh[s][j][e] = A1^T[e][j] * r1[e] (bf16, XOR-swizzled, b64 writes)
    {
        ushort* Vh = (ushort*)Buf;
        #pragma unroll
        for (int s = 0; s < 2; ++s)
            #pragma unroll
            for (int rp = 0; rp < 2; ++rp) {
                const int rb = 2 * w + rp;
                const int e0 = rb * 16 + q * 4;
                const uint mu = r1u[s][rb * 4 + q];
                #pragma unroll
                for (int cb = 0; cb < 4; ++cb) {
                    const f32x4 av = acc[s][rp][cb];
                    const float v0 = (mu & 0xFFu)       ? av.x : 0.f;
                    const float v1 = (mu & 0xFF00u)     ? av.y : 0.f;
                    const float v2 = (mu & 0xFF0000u)   ? av.z : 0.f;
                    const float v3 = (mu & 0xFF000000u) ? av.w : 0.f;
                    u32x2 p;
                    p.x = (uint)f2bf(v0) | ((uint)f2bf(v1) << 16);
                    p.y = (uint)f2bf(v2) | ((uint)f2bf(v3) << 16);
                    const int j = cb * 16 + m;
                    const int idx = j * 256 + (e0 ^ ((j & 7) << 3));
                    *(u32x2*)&Vh[s * 16384 + idx] = p;
                }
            }
    }
    __syncthreads();

    // ---- GEMM2: M^T = W1T @ (Vh as B) ; wave w owns rb_n in {2w, 2w+1}
    f32x4 acc2[2][2][4];
    #pragma unroll
    for (int s = 0; s < 2; ++s)
        #pragma unroll
        for (int rp = 0; rp < 2; ++rp)
            #pragma unroll
            for (int cb = 0; cb < 4; ++cb) acc2[s][rp][cb] = (f32x4){0.f, 0.f, 0.f, 0.f};

    {
        const bf16x8* W1Tf = (const bf16x8*)(ws + W1TA_OFF);
        const ushort* Vh = (const ushort*)Buf;
        #pragma unroll
        for (int ks = 0; ks < 8; ++ks) {
            bf16x8 a[2];
            #pragma unroll
            for (int rp = 0; rp < 2; ++rp) a[rp] = W1Tf[((2 * w + rp) * 8 + ks) * 64 + l];
            const int c0 = ks * 32 + q * 8;
            #pragma unroll
            for (int s = 0; s < 2; ++s)
                #pragma unroll
                for (int cb = 0; cb < 4; ++cb) {
                    const int j = cb * 16 + m;
                    const bf16x8 bb = *(const bf16x8*)&Vh[s * 16384 + j * 256 + (c0 ^ ((j & 7) << 3))];
                    #pragma unroll
                    for (int rp = 0; rp < 2; ++rp)
                        acc2[s][rp][cb] = __builtin_amdgcn_mfma_f32_16x16x32_bf16(a[rp], bb, acc2[s][rp][cb], 0, 0, 0);
                }
        }
    }

    // ---- reduce ||M_s||_F^2
    {
        float ps0 = 0.f, ps1 = 0.f;
        #pragma unroll
        for (int rp = 0; rp < 2; ++rp)
            #pragma unroll
            for (int cb = 0; cb < 4; ++cb) {
                const f32x4 a0 = acc2[0][rp][cb], a1 = acc2[1][rp][cb];
                ps0 = fmaf(a0.x, a0.x, ps0); ps0 = fmaf(a0.y, a0.y, ps0);
                ps0 = fmaf(a0.z, a0.z, ps0); ps0 = fmaf(a0.w, a0.w, ps0);
                ps1 = fmaf(a1.x, a1.x, ps1); ps1 = fmaf(a1.y, a1.y, ps1);
                ps1 = fmaf(a1.z, a1.z, ps1); ps1 = fmaf(a1.w, a1.w, ps1);
            }
        #pragma unroll
        for (int off = 32; off > 0; off >>= 1) {
            ps0 += __shfl_down(ps0, off, 64);
            ps1 += __shfl_down(ps1, off, 64);
        }
        if (l == 0) { red[0][w] = ps0; red[1][w] = ps1; }
    }
    __syncthreads();

    if (t < 128) {
        const int s = t >> 6, j = t & 63;
        float S = 0.f;
        #pragma unroll
        for (int i = 0; i < 8; ++i) S += red[s][i];
        const float* fws = (const float*)(ws + F_OFF);
        const float f = fws[(size_t)(b * 2 + s) * 64 + j];
        const float kv = kp[0];
        const float ksp = fmaxf(kv, 0.0f) + log1pf(expf(-fabsf(kv)));
        out[(size_t)(b * 2 + s) * 64 + j] = tanhf(ksp * f / (sqrtf(S) + 1e-4f));
    }
}

extern "C" void kernel_launch(void* const* d_in, const int* in_sizes, int n_in,
                              void* d_out, int out_size, void* d_ws, size_t ws_size,
                              hipStream_t stream) {
    const float* x  = (const float*)d_in[0];
    const float* W1 = (const float*)d_in[1];
    const float* b1 = (const float*)d_in[2];
    const float* W2 = (const float*)d_in[3];
    const float* b2 = (const float*)d_in[4];
    const float* W3 = (const float*)d_in[5];
    const float* b3 = (const float*)d_in[6];
    const float* kp = (const float*)d_in[7];
    char* ws = (char*)d_ws;

    k0_prep<<<72, 256, 0, stream>>>(W1, W2, W3, ws);
    k1_forward<<<1024, 256, 0, stream>>>(x, W1, b1, W2, b2, W3, b3, ws);
    k2_jac<<<4096, 512, 0, stream>>>(ws, kp, (float*)d_out);
}

// Round 7
// 211.803 us; speedup vs baseline: 1.4665x; 1.2545x over previous
//
#include <hip/hip_runtime.h>
#include <math.h>

// LipsNet R7. B=8192, D_IN=256, H=256, D_OUT=64.
// k0: swizzle W2^T, W1^T, W3 (k2 Jacobian frags, R4-validated) + NEW split hi/lo
//     A-frags of W1,W2,W3 for the MFMA forward.
// k1: split-bf16 MFMA forward (h = Whi*ahi + Wlo*ahi + Whi*alo, fp32 accum ->
//     ~2^-17 rel error; exact-enough masks + f). 16 samples/block, 256 thr.
// k2: R4-validated verbatim: 2 samples/block, 512 thr:
//     A1^T = W2T @ (W3 .* r2)^T ; M^T = W1T @ (A1^T .* r1);
//     out = tanh(softplus(k) * f / (||M||_F + eps)).
//
// MFMA 16x16x32 layouts (validated R2/R4):
//   A[m][k]: m = lane&15, k = (lane>>4)*8 + i
//   B[k][n]: n = lane&15, k = (lane>>4)*8 + i
//   C/D:     col = lane&15, row = (lane>>4)*4 + reg

typedef float  f32x4  __attribute__((ext_vector_type(4)));
typedef short  bf16x8 __attribute__((ext_vector_type(8)));
typedef unsigned int   uint;
typedef unsigned short ushort;
typedef unsigned char  uchar;
typedef uint   u32x4  __attribute__((ext_vector_type(4)));
typedef uint   u32x2  __attribute__((ext_vector_type(2)));

// ws byte offsets (R4-validated region unchanged; new regions appended)
#define W2TA_OFF 0u        // 16rb x 8ks x 64l x 16B = 131072
#define W1TA_OFF 131072u   // 131072
#define W3A_OFF  262144u   // 32768 (k2 B-use AND k1 layer-3 hi A-frags)
#define F_OFF    294912u   // 8192x64 fp32 = 2097152
#define R1_OFF   2392064u  // 8192x256 u8 = 2097152
#define R2_OFF   4489216u  // 2097152
#define W1AH_OFF 6586368u  // 131072
#define W1AL_OFF 6717440u  // 131072
#define W2AH_OFF 6848512u  // 131072
#define W2AL_OFF 6979584u  // 131072
#define W3AL_OFF 7110656u  // 32768
// total 7143424 B

__device__ __forceinline__ ushort f2bf(float f) {
    uint u = __builtin_bit_cast(uint, f);
    u += 0x7FFFu + ((u >> 16) & 1u);          // RNE
    return (ushort)(u >> 16);
}
__device__ __forceinline__ float bf2f(ushort h) {
    uint u = ((uint)h) << 16;
    return __builtin_bit_cast(float, u);
}
// halfword and-mask from two mask bytes of u at bit positions sh, sh+8
__device__ __forceinline__ uint hm2(uint u, int sh) {
    return (((u >> sh) & 0xFFu)   ? 0xFFFFu     : 0u) |
           (((u >> sh) & 0xFF00u) ? 0xFFFF0000u : 0u);
}

// ---------------- k0: weight prep ----------------
__global__ __launch_bounds__(256) void k0_prep(
    const float* __restrict__ W1, const float* __restrict__ W2,
    const float* __restrict__ W3, char* __restrict__ ws)
{
    const int id = blockIdx.x * 256 + threadIdx.x;
    if (id >= 34816) return;

    if (id < 16384) {
        // transposed A-frag gathers for k2 (R4-validated)
        const int fid = id & 8191;
        const int l = fid & 63, ks = (fid >> 6) & 7, rb = fid >> 9;
        const int m = l & 15, q = l >> 4;
        const int k0 = ks * 32 + q * 8;
        const float* M = (id < 8192) ? W2 : W1;
        const uint dstoff = (id < 8192) ? W2TA_OFF : W1TA_OFF;
        const int n = rb * 16 + m;
        ushort h[8];
        #pragma unroll
        for (int i = 0; i < 8; ++i) h[i] = f2bf(M[(k0 + i) * 256 + n]);
        u32x4 v;
        v.x = (uint)h[0] | ((uint)h[1] << 16);
        v.y = (uint)h[2] | ((uint)h[3] << 16);
        v.z = (uint)h[4] | ((uint)h[5] << 16);
        v.w = (uint)h[6] | ((uint)h[7] << 16);
        ((u32x4*)(ws + dstoff))[fid] = v;
        return;
    }

    // hi/lo A-frag pairs (row-major gathers) for k1 forward
    const float* M;
    uint hiOff, loOff;
    int fid;
    if (id < 18432)      { fid = id - 16384; M = W3; hiOff = W3A_OFF;  loOff = W3AL_OFF; }
    else if (id < 26624) { fid = id - 18432; M = W1; hiOff = W1AH_OFF; loOff = W1AL_OFF; }
    else                 { fid = id - 26624; M = W2; hiOff = W2AH_OFF; loOff = W2AL_OFF; }
    const int l = fid & 63, ks = (fid >> 6) & 7, rb = fid >> 9;
    const int m = l & 15, q = l >> 4;
    const int k0 = ks * 32 + q * 8;
    const float* p = M + (rb * 16 + m) * 256 + k0;
    ushort hh[8], ll[8];
    #pragma unroll
    for (int i = 0; i < 8; ++i) {
        const float v = p[i];
        const ushort h = f2bf(v);
        hh[i] = h;
        ll[i] = f2bf(v - bf2f(h));     // residual (exact subtraction)
    }
    u32x4 vh, vl;
    vh.x = (uint)hh[0] | ((uint)hh[1] << 16);
    vh.y = (uint)hh[2] | ((uint)hh[3] << 16);
    vh.z = (uint)hh[4] | ((uint)hh[5] << 16);
    vh.w = (uint)hh[6] | ((uint)hh[7] << 16);
    vl.x = (uint)ll[0] | ((uint)ll[1] << 16);
    vl.y = (uint)ll[2] | ((uint)ll[3] << 16);
    vl.z = (uint)ll[4] | ((uint)ll[5] << 16);
    vl.w = (uint)ll[6] | ((uint)ll[7] << 16);
    ((u32x4*)(ws + hiOff))[fid] = vh;
    ((u32x4*)(ws + loOff))[fid] = vl;
}

// ---------------- k1: split-bf16 MFMA forward, 16 samples/block ----------------
// K-loop over LDS input (fp32, stride 260): build a_hi/a_lo B-frags in registers,
// 3 MFMA per (ks, rb): Whi*ahi + Wlo*ahi + Whi*alo.
#define FWD_KLOOP(INOFF, HIOFF, LOOFF, NRB, ACC)                                   \
    {                                                                              \
        const bf16x8* WH = (const bf16x8*)(ws + (HIOFF));                          \
        const bf16x8* WL = (const bf16x8*)(ws + (LOOFF));                          \
        _Pragma("unroll")                                                          \
        for (int rr = 0; rr < (NRB); ++rr) ACC[rr] = (f32x4){0.f, 0.f, 0.f, 0.f};  \
        _Pragma("unroll")                                                          \
        for (int ks = 0; ks < 8; ++ks) {                                           \
            const int kk = ks * 32 + q * 8;                                        \
            float av[8];                                                           \
            *(f32x4*)&av[0] = *(const f32x4*)&SB[(INOFF) + m * 260 + kk];          \
            *(f32x4*)&av[4] = *(const f32x4*)&SB[(INOFF) + m * 260 + kk + 4];      \
            uint hw[4], lw[4];                                                     \
            _Pragma("unroll")                                                      \
            for (int pp = 0; pp < 4; ++pp) {                                       \
                const float a0 = av[2 * pp], a1 = av[2 * pp + 1];                  \
                const ushort h0 = f2bf(a0), h1 = f2bf(a1);                         \
                const float r0 = a0 - bf2f(h0), r1 = a1 - bf2f(h1);                \
                hw[pp] = (uint)h0 | ((uint)h1 << 16);                              \
                lw[pp] = (uint)f2bf(r0) | ((uint)f2bf(r1) << 16);                  \
            }                                                                      \
            const bf16x8 bhi = __builtin_bit_cast(bf16x8, (u32x4){hw[0], hw[1], hw[2], hw[3]}); \
            const bf16x8 blo = __builtin_bit_cast(bf16x8, (u32x4){lw[0], lw[1], lw[2], lw[3]}); \
            _Pragma("unroll")                                                      \
            for (int rr = 0; rr < (NRB); ++rr) {                                   \
                const int rb = ((NRB) == 4) ? (4 * w + rr) : w;                    \
                const bf16x8 ah = WH[(rb * 8 + ks) * 64 + l];                      \
                const bf16x8 al = WL[(rb * 8 + ks) * 64 + l];                      \
                ACC[rr] = __builtin_amdgcn_mfma_f32_16x16x32_bf16(ah, bhi, ACC[rr], 0, 0, 0); \
                ACC[rr] = __builtin_amdgcn_mfma_f32_16x16x32_bf16(al, bhi, ACC[rr], 0, 0, 0); \
                ACC[rr] = __builtin_amdgcn_mfma_f32_16x16x32_bf16(ah, blo, ACC[rr], 0, 0, 0); \
            }                                                                      \
        }                                                                          \
    }

__global__ __launch_bounds__(256) void k1_forward(
    const float* __restrict__ x,
    const float* __restrict__ b1, const float* __restrict__ b2,
    const float* __restrict__ b3, char* __restrict__ ws)
{
    __shared__ float SB[2 * 4160];   // [2][16 samples][260 fp32]; buf0: x then h2, buf1: h1
    const int t = threadIdx.x, w = t >> 6, l = t & 63;
    const int m = l & 15, q = l >> 4;
    const int g0 = blockIdx.x * 16;
    float* fws = (float*)(ws + F_OFF);
    uchar* r1g = (uchar*)(ws + R1_OFF);
    uchar* r2g = (uchar*)(ws + R2_OFF);

    // stage x (coalesced) into buf0
    {
        const f32x4* X4 = (const f32x4*)x;
        #pragma unroll
        for (int i = 0; i < 4; ++i) {
            const int idx = t + 256 * i;            // 0..1023
            const int g = idx >> 6, dq = idx & 63;
            *(f32x4*)&SB[g * 260 + dq * 4] = X4[(size_t)(g0 + g) * 64 + dq];
        }
    }
    __syncthreads();

    f32x4 acc[4];

    // ---- layer 1: h1 = relu(W1 @ x) ; masks r1 ; h1 fp32 -> buf1
    FWD_KLOOP(0, W1AH_OFF, W1AL_OFF, 4, acc)
    #pragma unroll
    for (int rr = 0; rr < 4; ++rr) {
        const int i0 = (4 * w + rr) * 16 + q * 4;
        const float4 bv = *(const float4*)(b1 + i0);
        const float v0 = acc[rr].x + bv.x, v1 = acc[rr].y + bv.y;
        const float v2 = acc[rr].z + bv.z, v3 = acc[rr].w + bv.w;
        const uint mv = (v0 > 0.f ? 1u : 0u) | (v1 > 0.f ? 0x100u : 0u) |
                        (v2 > 0.f ? 0x10000u : 0u) | (v3 > 0.f ? 0x1000000u : 0u);
        *(uint*)(r1g + (size_t)(g0 + m) * 256 + i0) = mv;
        const f32x4 rv = {fmaxf(v0, 0.f), fmaxf(v1, 0.f), fmaxf(v2, 0.f), fmaxf(v3, 0.f)};
        *(f32x4*)&SB[4160 + m * 260 + i0] = rv;
    }
    __syncthreads();

    // ---- layer 2: h2 = relu(W2 @ h1) ; masks r2 ; h2 fp32 -> buf0 (overlay x)
    FWD_KLOOP(4160, W2AH_OFF, W2AL_OFF, 4, acc)
    #pragma unroll
    for (int rr = 0; rr < 4; ++rr) {
        const int i0 = (4 * w + rr) * 16 + q * 4;
        const float4 bv = *(const float4*)(b2 + i0);
        const float v0 = acc[rr].x + bv.x, v1 = acc[rr].y + bv.y;
        const float v2 = acc[rr].z + bv.z, v3 = acc[rr].w + bv.w;
        const uint mv = (v0 > 0.f ? 1u : 0u) | (v1 > 0.f ? 0x100u : 0u) |
                        (v2 > 0.f ? 0x10000u : 0u) | (v3 > 0.f ? 0x1000000u : 0u);
        *(uint*)(r2g + (size_t)(g0 + m) * 256 + i0) = mv;
        const f32x4 rv = {fmaxf(v0, 0.f), fmaxf(v1, 0.f), fmaxf(v2, 0.f), fmaxf(v3, 0.f)};
        *(f32x4*)&SB[m * 260 + i0] = rv;
    }
    __syncthreads();

    // ---- layer 3: f = W3 @ h2 ; wave w owns row-block w (j = w*16 + q*4 + r)
    FWD_KLOOP(0, W3A_OFF, W3AL_OFF, 1, acc)
    {
        const int j0 = w * 16 + q * 4;
        const float4 bv = *(const float4*)(b3 + j0);
        const f32x4 ov = {acc[0].x + bv.x, acc[0].y + bv.y, acc[0].z + bv.z, acc[0].w + bv.w};
        *(f32x4*)(fws + (size_t)(g0 + m) * 64 + j0) = ov;
    }
}

// ---------------- k2: Jacobian norm + output, 2 samples/block, 512 thr (R4-validated) ----------------
__global__ __launch_bounds__(512, 4) void k2_jac(
    const char* __restrict__ ws, const float* __restrict__ kp,
    float* __restrict__ out)
{
    __shared__ char Buf[65536];            // per sample 32 KB: Bfrag1 then Vh (overlaid)
    __shared__ uint r1u[2][64], r2u[2][64];
    __shared__ float red[2][8];

    const int t = threadIdx.x, w = t >> 6, l = t & 63;
    const int m = l & 15, q = l >> 4;
    const int b = blockIdx.x;

    if (t < 128) {
        const int s = t >> 6, i = t & 63;
        r1u[s][i] = ((const uint*)(ws + R1_OFF))[(size_t)(b * 2 + s) * 64 + i];
        r2u[s][i] = ((const uint*)(ws + R2_OFF))[(size_t)(b * 2 + s) * 64 + i];
    }
    __syncthreads();

    // ---- Phase A: build Bf1[s] = (W3 .* r2_s)^T B-frags (8 frags per wave)
    {
        const u32x4* W3Av = (const u32x4*)(ws + W3A_OFF);
        u32x4* BufV = (u32x4*)Buf;
        #pragma unroll
        for (int ii = 0; ii < 8; ++ii) {
            const int id = w * 8 + ii;
            const int s = id >> 5, cb = (id >> 3) & 3, ks = id & 7;
            u32x4 v = W3Av[(cb * 8 + ks) * 64 + l];
            const int du = ks * 8 + q * 2;            // (d0>>2), d0 = ks*32+q*8
            const uint u0 = r2u[s][du], u1 = r2u[s][du + 1];
            v.x &= hm2(u0, 0);  v.y &= hm2(u0, 16);
            v.z &= hm2(u1, 0);  v.w &= hm2(u1, 16);
            BufV[s * 2048 + (cb * 8 + ks) * 64 + l] = v;
        }
    }
    __syncthreads();

    // ---- GEMM1: A1^T = W2T @ Bf1 ; wave w owns rb in {2w, 2w+1}, both samples, all cb
    f32x4 acc[2][2][4];                    // [s][rp][cb]
    #pragma unroll
    for (int s = 0; s < 2; ++s)
        #pragma unroll
        for (int rp = 0; rp < 2; ++rp)
            #pragma unroll
            for (int cb = 0; cb < 4; ++cb) acc[s][rp][cb] = (f32x4){0.f, 0.f, 0.f, 0.f};

    {
        const bf16x8* W2Tf = (const bf16x8*)(ws + W2TA_OFF);
        const bf16x8* BufF = (const bf16x8*)Buf;
        #pragma unroll
        for (int ks = 0; ks < 8; ++ks) {
            bf16x8 a[2];
            #pragma unroll
            for (int rp = 0; rp < 2; ++rp) a[rp] = W2Tf[((2 * w + rp) * 8 + ks) * 64 + l];
            #pragma unroll
            for (int s = 0; s < 2; ++s)
                #pragma unroll
                for (int cb = 0; cb < 4; ++cb) {
                    const bf16x8 bb = BufF[s * 2048 + (cb * 8 + ks) * 64 + l];
                    #pragma unroll
                    for (int rp = 0; rp < 2; ++rp)
                        acc[s][rp][cb] = __builtin_amdgcn_mfma_f32_16x16x32_bf16(a[rp], bb, acc[s][rp][cb], 0, 0, 0);
                }
        }
    }
    __syncthreads();   // all Bf1 reads done before overlay

    // ---- Phase C: Vh[s][j][e] = A1^T[e][j] * r1[e] (bf16, XOR-swizzled, b64 writes)
    {
        ushort* Vh = (ushort*)Buf;
        #pragma unroll
        for (int s = 0; s < 2; ++s)
            #pragma unroll
            for (int rp = 0; rp < 2; ++rp) {
                const int rb = 2 * w + rp;
                const int e0 = rb * 16 + q * 4;
                const uint mu = r1u[s][rb * 4 + q];
                #pragma unroll
                for (int cb = 0; cb < 4; ++cb) {
                    const f32x4 av = acc[s][rp][cb];
                    const float v0 = (mu & 0xFFu)       ? av.x : 0.f;
                    const float v1 = (mu & 0xFF00u)     ? av.y : 0.f;
                    const float v2 = (mu & 0xFF0000u)   ? av.z : 0.f;
                    const float v3 = (mu & 0xFF000000u) ? av.w : 0.f;
                    u32x2 p;
                    p.x = (uint)f2bf(v0) | ((uint)f2bf(v1) << 16);
                    p.y = (uint)f2bf(v2) | ((uint)f2bf(v3) << 16);
                    const int j = cb * 16 + m;
                    const int idx = j * 256 + (e0 ^ ((j & 7) << 3));
                    *(u32x2*)&Vh[s * 16384 + idx] = p;
                }
            }
    }
    __syncthreads();

    // ---- GEMM2: M^T = W1T @ (Vh as B) ; wave w owns rb_n in {2w, 2w+1}
    f32x4 acc2[2][2][4];
    #pragma unroll
    for (int s = 0; s < 2; ++s)
        #pragma unroll
        for (int rp = 0; rp < 2; ++rp)
            #pragma unroll
            for (int cb = 0; cb < 4; ++cb) acc2[s][rp][cb] = (f32x4){0.f, 0.f, 0.f, 0.f};

    {
        const bf16x8* W1Tf = (const bf16x8*)(ws + W1TA_OFF);
        const ushort* Vh = (const ushort*)Buf;
        #pragma unroll
        for (int ks = 0; ks < 8; ++ks) {
            bf16x8 a[2];
            #pragma unroll
            for (int rp = 0; rp < 2; ++rp) a[rp] = W1Tf[((2 * w + rp) * 8 + ks) * 64 + l];
            const int c0 = ks * 32 + q * 8;
            #pragma unroll
            for (int s = 0; s < 2; ++s)
                #pragma unroll
                for (int cb = 0; cb < 4; ++cb) {
                    const int j = cb * 16 + m;
                    const bf16x8 bb = *(const bf16x8*)&Vh[s * 16384 + j * 256 + (c0 ^ ((j & 7) << 3))];
                    #pragma unroll
                    for (int rp = 0; rp < 2; ++rp)
                        acc2[s][rp][cb] = __builtin_amdgcn_mfma_f32_16x16x32_bf16(a[rp], bb, acc2[s][rp][cb], 0, 0, 0);
                }
        }
    }

    // ---- reduce ||M_s||_F^2
    {
        float ps0 = 0.f, ps1 = 0.f;
        #pragma unroll
        for (int rp = 0; rp < 2; ++rp)
            #pragma unroll
            for (int cb = 0; cb < 4; ++cb) {
                const f32x4 a0 = acc2[0][rp][cb], a1 = acc2[1][rp][cb];
                ps0 = fmaf(a0.x, a0.x, ps0); ps0 = fmaf(a0.y, a0.y, ps0);
                ps0 = fmaf(a0.z, a0.z, ps0); ps0 = fmaf(a0.w, a0.w, ps0);
                ps1 = fmaf(a1.x, a1.x, ps1); ps1 = fmaf(a1.y, a1.y, ps1);
                ps1 = fmaf(a1.z, a1.z, ps1); ps1 = fmaf(a1.w, a1.w, ps1);
            }
        #pragma unroll
        for (int off = 32; off > 0; off >>= 1) {
            ps0 += __shfl_down(ps0, off, 64);
            ps1 += __shfl_down(ps1, off, 64);
        }
        if (l == 0) { red[0][w] = ps0; red[1][w] = ps1; }
    }
    __syncthreads();

    if (t < 128) {
        const int s = t >> 6, j = t & 63;
        float S = 0.f;
        #pragma unroll
        for (int i = 0; i < 8; ++i) S += red[s][i];
        const float* fws = (const float*)(ws + F_OFF);
        const float f = fws[(size_t)(b * 2 + s) * 64 + j];
        const float kv = kp[0];
        const float ksp = fmaxf(kv, 0.0f) + log1pf(expf(-fabsf(kv)));
        out[(size_t)(b * 2 + s) * 64 + j] = tanhf(ksp * f / (sqrtf(S) + 1e-4f));
    }
}

extern "C" void kernel_launch(void* const* d_in, const int* in_sizes, int n_in,
                              void* d_out, int out_size, void* d_ws, size_t ws_size,
                              hipStream_t stream) {
    const float* x  = (const float*)d_in[0];
    const float* W1 = (const float*)d_in[1];
    const float* b1 = (const float*)d_in[2];
    const float* W2 = (const float*)d_in[3];
    const float* b2 = (const float*)d_in[4];
    const float* W3 = (const float*)d_in[5];
    const float* b3 = (const float*)d_in[6];
    const float* kp = (const float*)d_in[7];
    char* ws = (char*)d_ws;

    k0_prep<<<136, 256, 0, stream>>>(W1, W2, W3, ws);
    k1_forward<<<512, 256, 0, stream>>>(x, b1, b2, b3, ws);
    k2_jac<<<4096, 512, 0, stream>>>(ws, kp, (float*)d_out);
}

// Round 8
// 203.560 us; speedup vs baseline: 1.5259x; 1.0405x over previous
//
#include <hip/hip_runtime.h>
#include <math.h>

// LipsNet R8. B=8192, D_IN=256, H=256, D_OUT=64.
// k0: weight frags (R4/R7-validated layouts).
// k1: split-bf16 MFMA forward; 512 thr / 8 waves, 2 row-blocks per wave ->
//     33 KB LDS, 4 blocks/CU = 32 waves/CU (R7 was latency-bound at 8).
// k2: Jacobian; 256 thr / 4 waves, 4 row-blocks per wave -> halves per-block
//     LDS B-panel reads (LDS was the dominant pipe at 60% in R7).
//
// MFMA 16x16x32 layouts (validated R2/R4):
//   A[m][k]: m = lane&15, k = (lane>>4)*8 + i
//   B[k][n]: n = lane&15, k = (lane>>4)*8 + i
//   C/D:     col = lane&15, row = (lane>>4)*4 + reg

typedef float  f32x4  __attribute__((ext_vector_type(4)));
typedef short  bf16x8 __attribute__((ext_vector_type(8)));
typedef unsigned int   uint;
typedef unsigned short ushort;
typedef unsigned char  uchar;
typedef uint   u32x4  __attribute__((ext_vector_type(4)));
typedef uint   u32x2  __attribute__((ext_vector_type(2)));

// ws byte offsets
#define W2TA_OFF 0u        // 16rb x 8ks x 64l x 16B = 131072
#define W1TA_OFF 131072u   // 131072
#define W3A_OFF  262144u   // 32768 (k2 B-use AND k1 layer-3 hi A-frags)
#define F_OFF    294912u   // 8192x64 fp32 = 2097152
#define R1_OFF   2392064u  // 8192x256 u8 = 2097152
#define R2_OFF   4489216u  // 2097152
#define W1AH_OFF 6586368u  // 131072
#define W1AL_OFF 6717440u  // 131072
#define W2AH_OFF 6848512u  // 131072
#define W2AL_OFF 6979584u  // 131072
#define W3AL_OFF 7110656u  // 32768
// total 7143424 B

__device__ __forceinline__ ushort f2bf(float f) {
    uint u = __builtin_bit_cast(uint, f);
    u += 0x7FFFu + ((u >> 16) & 1u);          // RNE
    return (ushort)(u >> 16);
}
__device__ __forceinline__ float bf2f(ushort h) {
    uint u = ((uint)h) << 16;
    return __builtin_bit_cast(float, u);
}
// halfword and-mask from two mask bytes of u at bit positions sh, sh+8
__device__ __forceinline__ uint hm2(uint u, int sh) {
    return (((u >> sh) & 0xFFu)   ? 0xFFFFu     : 0u) |
           (((u >> sh) & 0xFF00u) ? 0xFFFF0000u : 0u);
}

// ---------------- k0: weight prep (R7-validated) ----------------
__global__ __launch_bounds__(256) void k0_prep(
    const float* __restrict__ W1, const float* __restrict__ W2,
    const float* __restrict__ W3, char* __restrict__ ws)
{
    const int id = blockIdx.x * 256 + threadIdx.x;
    if (id >= 34816) return;

    if (id < 16384) {
        // transposed A-frag gathers for k2
        const int fid = id & 8191;
        const int l = fid & 63, ks = (fid >> 6) & 7, rb = fid >> 9;
        const int m = l & 15, q = l >> 4;
        const int k0 = ks * 32 + q * 8;
        const float* M = (id < 8192) ? W2 : W1;
        const uint dstoff = (id < 8192) ? W2TA_OFF : W1TA_OFF;
        const int n = rb * 16 + m;
        ushort h[8];
        #pragma unroll
        for (int i = 0; i < 8; ++i) h[i] = f2bf(M[(k0 + i) * 256 + n]);
        u32x4 v;
        v.x = (uint)h[0] | ((uint)h[1] << 16);
        v.y = (uint)h[2] | ((uint)h[3] << 16);
        v.z = (uint)h[4] | ((uint)h[5] << 16);
        v.w = (uint)h[6] | ((uint)h[7] << 16);
        ((u32x4*)(ws + dstoff))[fid] = v;
        return;
    }

    // hi/lo A-frag pairs (row-major gathers) for k1 forward
    const float* M;
    uint hiOff, loOff;
    int fid;
    if (id < 18432)      { fid = id - 16384; M = W3; hiOff = W3A_OFF;  loOff = W3AL_OFF; }
    else if (id < 26624) { fid = id - 18432; M = W1; hiOff = W1AH_OFF; loOff = W1AL_OFF; }
    else                 { fid = id - 26624; M = W2; hiOff = W2AH_OFF; loOff = W2AL_OFF; }
    const int l = fid & 63, ks = (fid >> 6) & 7, rb = fid >> 9;
    const int m = l & 15, q = l >> 4;
    const int k0 = ks * 32 + q * 8;
    const float* p = M + (rb * 16 + m) * 256 + k0;
    ushort hh[8], ll[8];
    #pragma unroll
    for (int i = 0; i < 8; ++i) {
        const float v = p[i];
        const ushort h = f2bf(v);
        hh[i] = h;
        ll[i] = f2bf(v - bf2f(h));     // residual (exact subtraction)
    }
    u32x4 vh, vl;
    vh.x = (uint)hh[0] | ((uint)hh[1] << 16);
    vh.y = (uint)hh[2] | ((uint)hh[3] << 16);
    vh.z = (uint)hh[4] | ((uint)hh[5] << 16);
    vh.w = (uint)hh[6] | ((uint)hh[7] << 16);
    vl.x = (uint)ll[0] | ((uint)ll[1] << 16);
    vl.y = (uint)ll[2] | ((uint)ll[3] << 16);
    vl.z = (uint)ll[4] | ((uint)ll[5] << 16);
    vl.w = (uint)ll[6] | ((uint)ll[7] << 16);
    ((u32x4*)(ws + hiOff))[fid] = vh;
    ((u32x4*)(ws + loOff))[fid] = vl;
}

// ---------------- k1: split-bf16 MFMA forward, 16 samples/block, 512 thr ----------------
// RBOF: row-block base for this wave (rb = RBOF + rr).
#define FWD_KLOOP(INOFF, HIOFF, LOOFF, NRB, RBOF, ACC)                             \
    {                                                                              \
        const bf16x8* WH = (const bf16x8*)(ws + (HIOFF));                          \
        const bf16x8* WL = (const bf16x8*)(ws + (LOOFF));                          \
        _Pragma("unroll")                                                          \
        for (int rr = 0; rr < (NRB); ++rr) ACC[rr] = (f32x4){0.f, 0.f, 0.f, 0.f};  \
        _Pragma("unroll")                                                          \
        for (int ks = 0; ks < 8; ++ks) {                                           \
            const int kk = ks * 32 + q * 8;                                        \
            float av[8];                                                           \
            *(f32x4*)&av[0] = *(const f32x4*)&SB[(INOFF) + m * 260 + kk];          \
            *(f32x4*)&av[4] = *(const f32x4*)&SB[(INOFF) + m * 260 + kk + 4];      \
            uint hw[4], lw[4];                                                     \
            _Pragma("unroll")                                                      \
            for (int pp = 0; pp < 4; ++pp) {                                       \
                const float a0 = av[2 * pp], a1 = av[2 * pp + 1];                  \
                const ushort h0 = f2bf(a0), h1 = f2bf(a1);                         \
                const float r0 = a0 - bf2f(h0), r1 = a1 - bf2f(h1);                \
                hw[pp] = (uint)h0 | ((uint)h1 << 16);                              \
                lw[pp] = (uint)f2bf(r0) | ((uint)f2bf(r1) << 16);                  \
            }                                                                      \
            const bf16x8 bhi = __builtin_bit_cast(bf16x8, (u32x4){hw[0], hw[1], hw[2], hw[3]}); \
            const bf16x8 blo = __builtin_bit_cast(bf16x8, (u32x4){lw[0], lw[1], lw[2], lw[3]}); \
            _Pragma("unroll")                                                      \
            for (int rr = 0; rr < (NRB); ++rr) {                                   \
                const int rb = (RBOF) + rr;                                        \
                const bf16x8 ah = WH[(rb * 8 + ks) * 64 + l];                      \
                const bf16x8 al = WL[(rb * 8 + ks) * 64 + l];                      \
                ACC[rr] = __builtin_amdgcn_mfma_f32_16x16x32_bf16(ah, bhi, ACC[rr], 0, 0, 0); \
                ACC[rr] = __builtin_amdgcn_mfma_f32_16x16x32_bf16(al, bhi, ACC[rr], 0, 0, 0); \
                ACC[rr] = __builtin_amdgcn_mfma_f32_16x16x32_bf16(ah, blo, ACC[rr], 0, 0, 0); \
            }                                                                      \
        }                                                                          \
    }

__global__ __launch_bounds__(512) void k1_forward(
    const float* __restrict__ x,
    const float* __restrict__ b1, const float* __restrict__ b2,
    const float* __restrict__ b3, char* __restrict__ ws)
{
    __shared__ float SB[2 * 4160];   // [2][16 samples][260 fp32]; buf0: x then h2, buf1: h1
    const int t = threadIdx.x, w = t >> 6, l = t & 63;
    const int m = l & 15, q = l >> 4;
    const int g0 = blockIdx.x * 16;
    float* fws = (float*)(ws + F_OFF);
    uchar* r1g = (uchar*)(ws + R1_OFF);
    uchar* r2g = (uchar*)(ws + R2_OFF);

    // stage x (coalesced) into buf0
    {
        const f32x4* X4 = (const f32x4*)x;
        #pragma unroll
        for (int i = 0; i < 2; ++i) {
            const int idx = t + 512 * i;            // 0..1023
            const int g = idx >> 6, dq = idx & 63;
            *(f32x4*)&SB[g * 260 + dq * 4] = X4[(size_t)(g0 + g) * 64 + dq];
        }
    }
    __syncthreads();

    f32x4 acc[2];

    // ---- layer 1: h1 = relu(W1 @ x) ; wave w owns rb in {2w, 2w+1}
    FWD_KLOOP(0, W1AH_OFF, W1AL_OFF, 2, 2 * w, acc)
    #pragma unroll
    for (int rr = 0; rr < 2; ++rr) {
        const int i0 = (2 * w + rr) * 16 + q * 4;
        const float4 bv = *(const float4*)(b1 + i0);
        const float v0 = acc[rr].x + bv.x, v1 = acc[rr].y + bv.y;
        const float v2 = acc[rr].z + bv.z, v3 = acc[rr].w + bv.w;
        const uint mv = (v0 > 0.f ? 1u : 0u) | (v1 > 0.f ? 0x100u : 0u) |
                        (v2 > 0.f ? 0x10000u : 0u) | (v3 > 0.f ? 0x1000000u : 0u);
        *(uint*)(r1g + (size_t)(g0 + m) * 256 + i0) = mv;
        const f32x4 rv = {fmaxf(v0, 0.f), fmaxf(v1, 0.f), fmaxf(v2, 0.f), fmaxf(v3, 0.f)};
        *(f32x4*)&SB[4160 + m * 260 + i0] = rv;
    }
    __syncthreads();

    // ---- layer 2: h2 = relu(W2 @ h1) ; -> buf0 (overlay x)
    FWD_KLOOP(4160, W2AH_OFF, W2AL_OFF, 2, 2 * w, acc)
    #pragma unroll
    for (int rr = 0; rr < 2; ++rr) {
        const int i0 = (2 * w + rr) * 16 + q * 4;
        const float4 bv = *(const float4*)(b2 + i0);
        const float v0 = acc[rr].x + bv.x, v1 = acc[rr].y + bv.y;
        const float v2 = acc[rr].z + bv.z, v3 = acc[rr].w + bv.w;
        const uint mv = (v0 > 0.f ? 1u : 0u) | (v1 > 0.f ? 0x100u : 0u) |
                        (v2 > 0.f ? 0x10000u : 0u) | (v3 > 0.f ? 0x1000000u : 0u);
        *(uint*)(r2g + (size_t)(g0 + m) * 256 + i0) = mv;
        const f32x4 rv = {fmaxf(v0, 0.f), fmaxf(v1, 0.f), fmaxf(v2, 0.f), fmaxf(v3, 0.f)};
        *(f32x4*)&SB[m * 260 + i0] = rv;
    }
    __syncthreads();

    // ---- layer 3: f = W3 @ h2 ; waves 0..3 own row-block w
    if (w < 4) {
        FWD_KLOOP(0, W3A_OFF, W3AL_OFF, 1, w, acc)
        const int j0 = w * 16 + q * 4;
        const float4 bv = *(const float4*)(b3 + j0);
        const f32x4 ov = {acc[0].x + bv.x, acc[0].y + bv.y, acc[0].z + bv.z, acc[0].w + bv.w};
        *(f32x4*)(fws + (size_t)(g0 + m) * 64 + j0) = ov;
    }
}

// ---------------- k2: Jacobian norm + output, 2 samples/block, 256 thr / 4 waves ----------------
__global__ __launch_bounds__(256, 2) void k2_jac(
    const char* __restrict__ ws, const float* __restrict__ kp,
    float* __restrict__ out)
{
    __shared__ char Buf[65536];            // per sample 32 KB: Bfrag1 then Vh (overlaid)
    __shared__ uint r1u[2][64], r2u[2][64];
    __shared__ float red[2][4];

    const int t = threadIdx.x, w = t >> 6, l = t & 63;
    const int m = l & 15, q = l >> 4;
    const int b = blockIdx.x;

    if (t < 128) {
        const int s = t >> 6, i = t & 63;
        r1u[s][i] = ((const uint*)(ws + R1_OFF))[(size_t)(b * 2 + s) * 64 + i];
        r2u[s][i] = ((const uint*)(ws + R2_OFF))[(size_t)(b * 2 + s) * 64 + i];
    }
    __syncthreads();

    // ---- Phase A: build Bf1[s] = (W3 .* r2_s)^T B-frags (16 frags per wave)
    {
        const u32x4* W3Av = (const u32x4*)(ws + W3A_OFF);
        u32x4* BufV = (u32x4*)Buf;
        #pragma unroll
        for (int ii = 0; ii < 16; ++ii) {
            const int id = w * 16 + ii;
            const int s = id >> 5, cb = (id >> 3) & 3, ks = id & 7;
            u32x4 v = W3Av[(cb * 8 + ks) * 64 + l];
            const int du = ks * 8 + q * 2;            // (d0>>2), d0 = ks*32+q*8
            const uint u0 = r2u[s][du], u1 = r2u[s][du + 1];
            v.x &= hm2(u0, 0);  v.y &= hm2(u0, 16);
            v.z &= hm2(u1, 0);  v.w &= hm2(u1, 16);
            BufV[s * 2048 + (cb * 8 + ks) * 64 + l] = v;
        }
    }
    __syncthreads();

    // ---- GEMM1: A1^T = W2T @ Bf1 ; wave w owns rb in {4w..4w+3}, both samples, all cb
    f32x4 acc[2][4][4];                    // [s][rp][cb]
    #pragma unroll
    for (int s = 0; s < 2; ++s)
        #pragma unroll
        for (int rp = 0; rp < 4; ++rp)
            #pragma unroll
            for (int cb = 0; cb < 4; ++cb) acc[s][rp][cb] = (f32x4){0.f, 0.f, 0.f, 0.f};

    {
        const bf16x8* W2Tf = (const bf16x8*)(ws + W2TA_OFF);
        const bf16x8* BufF = (const bf16x8*)Buf;
        #pragma unroll
        for (int ks = 0; ks < 8; ++ks) {
            bf16x8 a[4];
            #pragma unroll
            for (int rp = 0; rp < 4; ++rp) a[rp] = W2Tf[((4 * w + rp) * 8 + ks) * 64 + l];
            #pragma unroll
            for (int s = 0; s < 2; ++s)
                #pragma unroll
                for (int cb = 0; cb < 4; ++cb) {
                    const bf16x8 bb = BufF[s * 2048 + (cb * 8 + ks) * 64 + l];
                    #pragma unroll
                    for (int rp = 0; rp < 4; ++rp)
                        acc[s][rp][cb] = __builtin_amdgcn_mfma_f32_16x16x32_bf16(a[rp], bb, acc[s][rp][cb], 0, 0, 0);
                }
        }
    }
    __syncthreads();   // all Bf1 reads done before overlay

    // ---- Phase C: Vh[s][j][e] = A1^T[e][j] * r1[e] (bf16, XOR-swizzled, b64 writes)
    {
        ushort* Vh = (ushort*)Buf;
        #pragma unroll
        for (int s = 0; s < 2; ++s)
            #pragma unroll
            for (int rp = 0; rp < 4; ++rp) {
                const int rb = 4 * w + rp;
                const int e0 = rb * 16 + q * 4;
                const uint mu = r1u[s][rb * 4 + q];
                #pragma unroll
                for (int cb = 0; cb < 4; ++cb) {
                    const f32x4 av = acc[s][rp][cb];
                    const float v0 = (mu & 0xFFu)       ? av.x : 0.f;
                    const float v1 = (mu & 0xFF00u)     ? av.y : 0.f;
                    const float v2 = (mu & 0xFF0000u)   ? av.z : 0.f;
                    const float v3 = (mu & 0xFF000000u) ? av.w : 0.f;
                    u32x2 p;
                    p.x = (uint)f2bf(v0) | ((uint)f2bf(v1) << 16);
                    p.y = (uint)f2bf(v2) | ((uint)f2bf(v3) << 16);
                    const int j = cb * 16 + m;
                    const int idx = j * 256 + (e0 ^ ((j & 7) << 3));
                    *(u32x2*)&Vh[s * 16384 + idx] = p;
                }
            }
    }
    __syncthreads();

    // ---- GEMM2: M^T = W1T @ (Vh as B) ; wave w owns rb_n in {4w..4w+3}
    f32x4 acc2[2][4][4];
    #pragma unroll
    for (int s = 0; s < 2; ++s)
        #pragma unroll
        for (int rp = 0; rp < 4; ++rp)
            #pragma unroll
            for (int cb = 0; cb < 4; ++cb) acc2[s][rp][cb] = (f32x4){0.f, 0.f, 0.f, 0.f};

    {
        const bf16x8* W1Tf = (const bf16x8*)(ws + W1TA_OFF);
        const ushort* Vh = (const ushort*)Buf;
        #pragma unroll
        for (int ks = 0; ks < 8; ++ks) {
            bf16x8 a[4];
            #pragma unroll
            for (int rp = 0; rp < 4; ++rp) a[rp] = W1Tf[((4 * w + rp) * 8 + ks) * 64 + l];
            const int c0 = ks * 32 + q * 8;
            #pragma unroll
            for (int s = 0; s < 2; ++s)
                #pragma unroll
                for (int cb = 0; cb < 4; ++cb) {
                    const int j = cb * 16 + m;
                    const bf16x8 bb = *(const bf16x8*)&Vh[s * 16384 + j * 256 + (c0 ^ ((j & 7) << 3))];
                    #pragma unroll
                    for (int rp = 0; rp < 4; ++rp)
                        acc2[s][rp][cb] = __builtin_amdgcn_mfma_f32_16x16x32_bf16(a[rp], bb, acc2[s][rp][cb], 0, 0, 0);
                }
        }
    }

    // ---- reduce ||M_s||_F^2
    {
        float ps0 = 0.f, ps1 = 0.f;
        #pragma unroll
        for (int rp = 0; rp < 4; ++rp)
            #pragma unroll
            for (int cb = 0; cb < 4; ++cb) {
                const f32x4 a0 = acc2[0][rp][cb], a1 = acc2[1][rp][cb];
                ps0 = fmaf(a0.x, a0.x, ps0); ps0 = fmaf(a0.y, a0.y, ps0);
                ps0 = fmaf(a0.z, a0.z, ps0); ps0 = fmaf(a0.w, a0.w, ps0);
                ps1 = fmaf(a1.x, a1.x, ps1); ps1 = fmaf(a1.y, a1.y, ps1);
                ps1 = fmaf(a1.z, a1.z, ps1); ps1 = fmaf(a1.w, a1.w, ps1);
            }
        #pragma unroll
        for (int off = 32; off > 0; off >>= 1) {
            ps0 += __shfl_down(ps0, off, 64);
            ps1 += __shfl_down(ps1, off, 64);
        }
        if (l == 0) { red[0][w] = ps0; red[1][w] = ps1; }
    }
    __syncthreads();

    if (t < 128) {
        const int s = t >> 6, j = t & 63;
        const float S = red[s][0] + red[s][1] + red[s][2] + red[s][3];
        const float* fws = (const float*)(ws + F_OFF);
        const float f = fws[(size_t)(b * 2 + s) * 64 + j];
        const float kv = kp[0];
        const float ksp = fmaxf(kv, 0.0f) + log1pf(expf(-fabsf(kv)));
        out[(size_t)(b * 2 + s) * 64 + j] = tanhf(ksp * f / (sqrtf(S) + 1e-4f));
    }
}

extern "C" void kernel_launch(void* const* d_in, const int* in_sizes, int n_in,
                              void* d_out, int out_size, void* d_ws, size_t ws_size,
                              hipStream_t stream) {
    const float* x  = (const float*)d_in[0];
    const float* W1 = (const float*)d_in[1];
    const float* b1 = (const float*)d_in[2];
    const float* W2 = (const float*)d_in[3];
    const float* b2 = (const float*)d_in[4];
    const float* W3 = (const float*)d_in[5];
    const float* b3 = (const float*)d_in[6];
    const float* kp = (const float*)d_in[7];
    char* ws = (char*)d_ws;

    k0_prep<<<136, 256, 0, stream>>>(W1, W2, W3, ws);
    k1_forward<<<512, 512, 0, stream>>>(x, b1, b2, b3, ws);
    k2_jac<<<4096, 256, 0, stream>>>(ws, kp, (float*)d_out);
}